// Round 1
// baseline (248.621 us; speedup 1.0000x reference)
//
#include <hip/hip_runtime.h>

#define IN_DIM  2048   // K
#define OUT_DIM 2048   // N
#define MROWS   8192   // M = B*S
#define RANK    4

typedef unsigned short ushort_t;
typedef __attribute__((ext_vector_type(8))) short  short8;   // 8 bf16 (4 VGPRs)
typedef __attribute__((ext_vector_type(4))) float  floatx4;  // MFMA acc

__device__ __forceinline__ unsigned short f2bf(float f) {
  union { float f; unsigned int u; } v; v.f = f;
  unsigned int r = v.u + 0x7fffu + ((v.u >> 16) & 1u);  // RNE
  return (unsigned short)(r >> 16);
}

__device__ __forceinline__ void gload16(const ushort_t* g, short* l) {
  __builtin_amdgcn_global_load_lds(
      (const __attribute__((address_space(1))) void*)g,
      (__attribute__((address_space(3))) void*)l, 16, 0, 0);
}

// ---- kernel 1: rank coefficients c[r] = g[r] / (||A[:,r]|| * ||B[r,:]||) ----
__global__ void coef_kernel(const float* __restrict__ sA, const float* __restrict__ sB,
                            const float* __restrict__ mag, float* __restrict__ cOut) {
  __shared__ float part[8][256];
  __shared__ float tot[8];
  int t = threadIdx.x;
  float sa[4] = {0.f, 0.f, 0.f, 0.f};
  for (int o = t; o < OUT_DIM; o += 256) {
    float4 v = *(const float4*)(sA + o * 4);
    sa[0] += v.x * v.x; sa[1] += v.y * v.y; sa[2] += v.z * v.z; sa[3] += v.w * v.w;
  }
  float sb[4] = {0.f, 0.f, 0.f, 0.f};
  for (int r = 0; r < 4; ++r)
    for (int i = t; i < IN_DIM; i += 256) { float v = sB[r * IN_DIM + i]; sb[r] += v * v; }
  for (int q = 0; q < 4; ++q) { part[q][t] = sa[q]; part[4 + q][t] = sb[q]; }
  __syncthreads();
  if (t < 8) { float s = 0.f; for (int j = 0; j < 256; ++j) s += part[t][j]; tot[t] = s; }
  __syncthreads();
  if (t < 4) {
    float g  = log1pf(expf(mag[t])) + 1e-6f;        // softplus + mag_eps
    float na = fmaxf(sqrtf(tot[t]),     1e-6f);
    float nb = fmaxf(sqrtf(tot[4 + t]), 1e-6f);
    cOut[t] = g / (na * nb);
  }
}

// ---- kernel 2: W[o,i] = lut[idx[o,i]] * sum_r |A[o,r]|*c[r]*|B[r,i]|  (bf16) ----
__global__ void build_w_kernel(const int* __restrict__ idx, const float* __restrict__ lut,
                               const float* __restrict__ sA, const float* __restrict__ sB,
                               const float* __restrict__ c, ushort_t* __restrict__ W) {
  __shared__ float aA[4];
  __shared__ float lutS[16];
  int o = blockIdx.x;
  int t = threadIdx.x;
  if (t < 4)  aA[t]   = fabsf(sA[o * 4 + t]) * c[t];
  if (t < 16) lutS[t] = lut[t];
  __syncthreads();
  int i = t * 8;
  const int* ip = idx + (size_t)o * IN_DIM + i;
  unsigned short u[8];
  #pragma unroll
  for (int j = 0; j < 8; ++j) {
    float s = aA[0] * fabsf(sB[0 * IN_DIM + i + j])
            + aA[1] * fabsf(sB[1 * IN_DIM + i + j])
            + aA[2] * fabsf(sB[2 * IN_DIM + i + j])
            + aA[3] * fabsf(sB[3 * IN_DIM + i + j]);
    u[j] = f2bf(lutS[ip[j]] * s);
  }
  uint4 o4;
  o4.x = (unsigned)u[0] | ((unsigned)u[1] << 16);
  o4.y = (unsigned)u[2] | ((unsigned)u[3] << 16);
  o4.z = (unsigned)u[4] | ((unsigned)u[5] << 16);
  o4.w = (unsigned)u[6] | ((unsigned)u[7] << 16);
  *(uint4*)(W + (size_t)o * IN_DIM + i) = o4;
}

// ---- kernel 3: cast x fp32 -> bf16 ----
__global__ void cast_kernel(const float* __restrict__ x, ushort_t* __restrict__ xb) {
  size_t i = ((size_t)blockIdx.x * 256 + threadIdx.x) * 8;
  float4 a = *(const float4*)(x + i);
  float4 b = *(const float4*)(x + i + 4);
  uint4 o4;
  o4.x = (unsigned)f2bf(a.x) | ((unsigned)f2bf(a.y) << 16);
  o4.y = (unsigned)f2bf(a.z) | ((unsigned)f2bf(a.w) << 16);
  o4.z = (unsigned)f2bf(b.x) | ((unsigned)f2bf(b.y) << 16);
  o4.w = (unsigned)f2bf(b.z) | ((unsigned)f2bf(b.w) << 16);
  *(uint4*)(xb + i) = o4;
}

// ---- kernel 4: C[M,N] = A[M,K] * W[N,K]^T + bias  (m97 structure) ----
__global__ __launch_bounds__(256) void gemm_kernel(const ushort_t* __restrict__ A,
                                                   const ushort_t* __restrict__ W,
                                                   const float* __restrict__ bias,
                                                   float* __restrict__ C) {
  __shared__ short As[128 * 32];  // 128 rows x BK=32, row-major, NO padding (global_load_lds)
  __shared__ short Bs[128 * 32];
  const int t    = threadIdx.x;
  const int lane = t & 63;
  const int wid  = t >> 6;
  const int wr   = wid >> 1;   // 2x2 wave grid, each wave owns 64x64
  const int wc   = wid & 1;
  const int rowBase = blockIdx.y * 128;
  const int colBase = blockIdx.x * 128;

  floatx4 acc[4][4];
  #pragma unroll
  for (int i = 0; i < 4; ++i)
    #pragma unroll
    for (int j = 0; j < 4; ++j) acc[i][j] = (floatx4){0.f, 0.f, 0.f, 0.f};

  // staging: chunk j (0..511) = 16B; row=j>>2, k-elem-offset=(j&3)*8; LDS byte = j*16
  const int j0 = t, j1 = t + 256;
  const ushort_t* a0 = A + (size_t)(rowBase + (j0 >> 2)) * IN_DIM + (j0 & 3) * 8;
  const ushort_t* a1 = A + (size_t)(rowBase + (j1 >> 2)) * IN_DIM + (j1 & 3) * 8;
  const ushort_t* b0 = W + (size_t)(colBase + (j0 >> 2)) * IN_DIM + (j0 & 3) * 8;
  const ushort_t* b1 = W + (size_t)(colBase + (j1 >> 2)) * IN_DIM + (j1 & 3) * 8;
  short* lA0 = As + (wid * 64) * 8;          // wave-uniform LDS bases (elem units)
  short* lA1 = As + (256 + wid * 64) * 8;
  short* lB0 = Bs + (wid * 64) * 8;
  short* lB1 = Bs + (256 + wid * 64) * 8;

  const int rA   = lane & 15;        // row within 16x16 tile
  const int kOff = (lane >> 4) * 8;  // k start for this lane's 8 elems

  for (int k0 = 0; k0 < IN_DIM; k0 += 32) {
    gload16(a0 + k0, lA0);
    gload16(a1 + k0, lA1);
    gload16(b0 + k0, lB0);
    gload16(b1 + k0, lB1);
    __syncthreads();   // compiler emits vmcnt(0) drain here — correct for global_load_lds

    short8 af[4], bf[4];
    #pragma unroll
    for (int mi = 0; mi < 4; ++mi)
      af[mi] = *(const short8*)(As + (wr * 64 + mi * 16 + rA) * 32 + kOff);
    #pragma unroll
    for (int ni = 0; ni < 4; ++ni)
      bf[ni] = *(const short8*)(Bs + (wc * 64 + ni * 16 + rA) * 32 + kOff);
    #pragma unroll
    for (int mi = 0; mi < 4; ++mi)
      #pragma unroll
      for (int ni = 0; ni < 4; ++ni)
        acc[mi][ni] = __builtin_amdgcn_mfma_f32_16x16x32_bf16(af[mi], bf[ni], acc[mi][ni], 0, 0, 0);
    __syncthreads();
  }

  // epilogue: D col = lane&15, row = (lane>>4)*4 + reg  (m89/m91-verified layout)
  const int mB = rowBase + wr * 64 + (lane >> 4) * 4;
  const int nB = colBase + wc * 64 + (lane & 15);
  #pragma unroll
  for (int ni = 0; ni < 4; ++ni) {
    float bv = bias[nB + ni * 16];
    #pragma unroll
    for (int mi = 0; mi < 4; ++mi)
      #pragma unroll
      for (int r = 0; r < 4; ++r)
        C[(size_t)(mB + mi * 16 + r) * OUT_DIM + (nB + ni * 16)] = acc[mi][ni][r] + bv;
  }
}

extern "C" void kernel_launch(void* const* d_in, const int* in_sizes, int n_in,
                              void* d_out, int out_size, void* d_ws, size_t ws_size,
                              hipStream_t stream) {
  const float* x    = (const float*)d_in[0];
  const int*   idx  = (const int*)d_in[1];
  const float* lut  = (const float*)d_in[2];
  const float* sA   = (const float*)d_in[3];
  const float* sB   = (const float*)d_in[4];
  const float* mag  = (const float*)d_in[5];
  const float* bias = (const float*)d_in[6];
  float* y = (float*)d_out;

  char* ws = (char*)d_ws;
  float*    c  = (float*)ws;                                            // 16 B
  ushort_t* W  = (ushort_t*)(ws + 256);                                 // 8 MiB
  ushort_t* xb = (ushort_t*)(ws + 256 + (size_t)OUT_DIM * IN_DIM * 2);  // 32 MiB

  coef_kernel<<<1, 256, 0, stream>>>(sA, sB, mag, c);
  build_w_kernel<<<OUT_DIM, 256, 0, stream>>>(idx, lut, sA, sB, c, W);
  cast_kernel<<<(MROWS * IN_DIM) / (256 * 8), 256, 0, stream>>>(x, xb);
  dim3 g(OUT_DIM / 128, MROWS / 128);
  gemm_kernel<<<g, 256, 0, stream>>>(xb, W, bias, y);
}

// Round 2
// 243.076 us; speedup vs baseline: 1.0228x; 1.0228x over previous
//
#include <hip/hip_runtime.h>

#define IN_DIM  2048   // K
#define OUT_DIM 2048   // N
#define MROWS   8192   // M = B*S
#define RANK    4

typedef unsigned short ushort_t;
typedef __attribute__((ext_vector_type(8))) short  short8;   // 8 bf16 (4 VGPRs)
typedef __attribute__((ext_vector_type(4))) float  floatx4;  // MFMA acc

__device__ __forceinline__ unsigned short f2bf(float f) {
  union { float f; unsigned int u; } v; v.f = f;
  unsigned int r = v.u + 0x7fffu + ((v.u >> 16) & 1u);  // RNE
  return (unsigned short)(r >> 16);
}

__device__ __forceinline__ void gload16(const ushort_t* g, short* l) {
  __builtin_amdgcn_global_load_lds(
      (const __attribute__((address_space(1))) void*)g,
      (__attribute__((address_space(3))) void*)l, 16, 0, 0);
}

// ---- kernel 1: rank coefficients c[r] = softplus(mag)/(||A[:,r]|| * ||B[r,:]||) ----
__global__ void coef_kernel(const float* __restrict__ sA, const float* __restrict__ sB,
                            const float* __restrict__ mag, float* __restrict__ cOut) {
  __shared__ float part[8][256];
  __shared__ float tot[8];
  int t = threadIdx.x;
  float sa[4] = {0.f, 0.f, 0.f, 0.f};
  for (int o = t; o < OUT_DIM; o += 256) {
    float4 v = *(const float4*)(sA + o * 4);
    sa[0] += v.x * v.x; sa[1] += v.y * v.y; sa[2] += v.z * v.z; sa[3] += v.w * v.w;
  }
  float sb[4] = {0.f, 0.f, 0.f, 0.f};
  for (int r = 0; r < 4; ++r)
    for (int i = t; i < IN_DIM; i += 256) { float v = sB[r * IN_DIM + i]; sb[r] += v * v; }
  for (int q = 0; q < 4; ++q) { part[q][t] = sa[q]; part[4 + q][t] = sb[q]; }
  __syncthreads();
  if (t < 8) { float s = 0.f; for (int j = 0; j < 256; ++j) s += part[t][j]; tot[t] = s; }
  __syncthreads();
  if (t < 4) {
    float g  = log1pf(expf(mag[t])) + 1e-6f;        // softplus + mag_eps
    float na = fmaxf(sqrtf(tot[t]),     1e-6f);
    float nb = fmaxf(sqrtf(tot[4 + t]), 1e-6f);
    cOut[t] = g / (na * nb);
  }
}

// ---- kernel 2 (fused): blocks [0,8192): cast x->bf16; blocks [8192,10240): build W ----
__global__ void prep_kernel(const float* __restrict__ x, ushort_t* __restrict__ xb,
                            const int* __restrict__ idx, const float* __restrict__ lut,
                            const float* __restrict__ sA, const float* __restrict__ sB,
                            const float* __restrict__ c, ushort_t* __restrict__ W) {
  int t = threadIdx.x;
  if (blockIdx.x < 8192) {
    size_t i = ((size_t)blockIdx.x * 256 + t) * 8;
    float4 a = *(const float4*)(x + i);
    float4 b = *(const float4*)(x + i + 4);
    uint4 o4;
    o4.x = (unsigned)f2bf(a.x) | ((unsigned)f2bf(a.y) << 16);
    o4.y = (unsigned)f2bf(a.z) | ((unsigned)f2bf(a.w) << 16);
    o4.z = (unsigned)f2bf(b.x) | ((unsigned)f2bf(b.y) << 16);
    o4.w = (unsigned)f2bf(b.z) | ((unsigned)f2bf(b.w) << 16);
    *(uint4*)(xb + i) = o4;
  } else {
    __shared__ float aA[4];
    __shared__ float lutS[16];
    int o = blockIdx.x - 8192;
    if (t < 4)  aA[t]   = fabsf(sA[o * 4 + t]) * c[t];
    if (t < 16) lutS[t] = lut[t];
    __syncthreads();
    int i = t * 8;
    const int4* ip4 = (const int4*)(idx + (size_t)o * IN_DIM + i);
    int4 i0 = ip4[0], i1 = ip4[1];
    int ii[8] = {i0.x, i0.y, i0.z, i0.w, i1.x, i1.y, i1.z, i1.w};
    unsigned short u[8];
    #pragma unroll
    for (int j = 0; j < 8; ++j) {
      float s = aA[0] * fabsf(sB[0 * IN_DIM + i + j])
              + aA[1] * fabsf(sB[1 * IN_DIM + i + j])
              + aA[2] * fabsf(sB[2 * IN_DIM + i + j])
              + aA[3] * fabsf(sB[3 * IN_DIM + i + j]);
      u[j] = f2bf(lutS[ii[j]] * s);
    }
    uint4 o4;
    o4.x = (unsigned)u[0] | ((unsigned)u[1] << 16);
    o4.y = (unsigned)u[2] | ((unsigned)u[3] << 16);
    o4.z = (unsigned)u[4] | ((unsigned)u[5] << 16);
    o4.w = (unsigned)u[6] | ((unsigned)u[7] << 16);
    *(uint4*)(W + (size_t)o * IN_DIM + i) = o4;
  }
}

// ---- kernel 3: C[M,N] = A[M,K] * W[N,K]^T + bias ----
// LDS layout per 128x32 tile: chunk j (16B) at byte j*16; row=j>>2, slot=j&3.
// Slot c of row r holds k-chunk c ^ ((r>>1)&3)  -> frag reads are 2-way (free),
// staging still fetches whole 64B lines (swizzle permutes within the line).
__global__ __launch_bounds__(256) void gemm_kernel(const ushort_t* __restrict__ A,
                                                   const ushort_t* __restrict__ W,
                                                   const float* __restrict__ bias,
                                                   float* __restrict__ C) {
  __shared__ short As[128 * 32];
  __shared__ short Bs[128 * 32];
  const int t    = threadIdx.x;
  const int lane = t & 63;
  const int wid  = t >> 6;
  const int wr   = wid >> 1;   // 2x2 wave grid, each wave owns 64x64
  const int wc   = wid & 1;
  const int rowBase = blockIdx.y * 128;
  const int colBase = blockIdx.x * 128;

  floatx4 acc[4][4];
  #pragma unroll
  for (int i = 0; i < 4; ++i)
    #pragma unroll
    for (int j = 0; j < 4; ++j) acc[i][j] = (floatx4){0.f, 0.f, 0.f, 0.f};

  // staging: chunk j0=t (rows 0..63 of tile), j1=t+256 (rows 64..127)
  const int row0 = t >> 2;
  const int c0   = t & 3;
  const int kc0  = c0 ^ ((row0 >> 1) & 3);   // XOR swizzle (same for j1: row1=row0+64)
  const ushort_t* a0 = A + (size_t)(rowBase + row0) * IN_DIM + kc0 * 8;
  const ushort_t* a1 = A + (size_t)(rowBase + row0 + 64) * IN_DIM + kc0 * 8;
  const ushort_t* b0 = W + (size_t)(colBase + row0) * IN_DIM + kc0 * 8;
  const ushort_t* b1 = W + (size_t)(colBase + row0 + 64) * IN_DIM + kc0 * 8;
  short* lA0 = As + (wid * 64) * 8;          // wave-uniform LDS bases (elem units)
  short* lA1 = As + (256 + wid * 64) * 8;
  short* lB0 = Bs + (wid * 64) * 8;
  short* lB1 = Bs + (256 + wid * 64) * 8;

  const int rA   = lane & 15;                       // row within 16x16 tile
  const int slot = ((rA >> 1) & 3) ^ (lane >> 4);   // swizzled k-slot for this lane
  const int kOff = slot * 8;

  for (int k0 = 0; k0 < IN_DIM; k0 += 32) {
    gload16(a0 + k0, lA0);
    gload16(a1 + k0, lA1);
    gload16(b0 + k0, lB0);
    gload16(b1 + k0, lB1);
    __syncthreads();

    short8 af[4], bf[4];
    #pragma unroll
    for (int mi = 0; mi < 4; ++mi)
      af[mi] = *(const short8*)(As + (wr * 64 + mi * 16 + rA) * 32 + kOff);
    #pragma unroll
    for (int ni = 0; ni < 4; ++ni)
      bf[ni] = *(const short8*)(Bs + (wc * 64 + ni * 16 + rA) * 32 + kOff);
    #pragma unroll
    for (int mi = 0; mi < 4; ++mi)
      #pragma unroll
      for (int ni = 0; ni < 4; ++ni)
        acc[mi][ni] = __builtin_amdgcn_mfma_f32_16x16x32_bf16(af[mi], bf[ni], acc[mi][ni], 0, 0, 0);
    __syncthreads();
  }

  // epilogue: D col = lane&15, row = (lane>>4)*4 + reg
  const int mB = rowBase + wr * 64 + (lane >> 4) * 4;
  const int nB = colBase + wc * 64 + (lane & 15);
  #pragma unroll
  for (int ni = 0; ni < 4; ++ni) {
    float bv = bias[nB + ni * 16];
    #pragma unroll
    for (int mi = 0; mi < 4; ++mi)
      #pragma unroll
      for (int r = 0; r < 4; ++r)
        C[(size_t)(mB + mi * 16 + r) * OUT_DIM + (nB + ni * 16)] = acc[mi][ni][r] + bv;
  }
}

extern "C" void kernel_launch(void* const* d_in, const int* in_sizes, int n_in,
                              void* d_out, int out_size, void* d_ws, size_t ws_size,
                              hipStream_t stream) {
  const float* x    = (const float*)d_in[0];
  const int*   idx  = (const int*)d_in[1];
  const float* lut  = (const float*)d_in[2];
  const float* sA   = (const float*)d_in[3];
  const float* sB   = (const float*)d_in[4];
  const float* mag  = (const float*)d_in[5];
  const float* bias = (const float*)d_in[6];
  float* y = (float*)d_out;

  char* ws = (char*)d_ws;
  float*    c  = (float*)ws;                                            // 16 B
  ushort_t* W  = (ushort_t*)(ws + 256);                                 // 8 MiB
  ushort_t* xb = (ushort_t*)(ws + 256 + (size_t)OUT_DIM * IN_DIM * 2);  // 32 MiB

  coef_kernel<<<1, 256, 0, stream>>>(sA, sB, mag, c);
  prep_kernel<<<8192 + OUT_DIM, 256, 0, stream>>>(x, xb, idx, lut, sA, sB, c, W);
  dim3 g(OUT_DIM / 128, MROWS / 128);
  gemm_kernel<<<g, 256, 0, stream>>>(xb, W, bias, y);
}